// Round 15
// baseline (190.211 us; speedup 1.0000x reference)
//
#include <hip/hip_runtime.h>

typedef __attribute__((ext_vector_type(8))) short short8;
typedef __attribute__((ext_vector_type(4))) short short4v;
typedef __attribute__((ext_vector_type(4))) unsigned short ushort4v;
typedef __attribute__((ext_vector_type(4))) float f32x4;
typedef __attribute__((ext_vector_type(4))) unsigned int u32x4;

static __device__ __forceinline__ unsigned short f2bf(float f){
  unsigned u = __builtin_bit_cast(unsigned, f);
  unsigned r = u + 0x7fffu + ((u >> 16) & 1u);
  return (unsigned short)(r >> 16);
}

static __device__ __forceinline__ float exp2_fast(float x){
  float r; asm("v_exp_f32 %0, %1" : "=v"(r) : "v"(x)); return r;
}

static __device__ __forceinline__ void g2lds16(const unsigned short* g, unsigned short* l){
  __builtin_amdgcn_global_load_lds(
      (const __attribute__((address_space(1))) void*)g,
      (__attribute__((address_space(3))) void*)l, 16, 0, 0);
}

// ---------------- cast fp32 -> bf16 (vectorized) ----------------
__global__ __launch_bounds__(256) void cast_bf16_kernel(const float* __restrict__ in,
                                                        unsigned short* __restrict__ out, int n8){
  int i = blockIdx.x * 256 + threadIdx.x;
  if (i >= n8) return;
  const float4* p = (const float4*)in + (size_t)i * 2;
  float4 a = p[0], b = p[1];
  short8 o;
  o[0] = (short)f2bf(a.x); o[1] = (short)f2bf(a.y); o[2] = (short)f2bf(a.z); o[3] = (short)f2bf(a.w);
  o[4] = (short)f2bf(b.x); o[5] = (short)f2bf(b.y); o[6] = (short)f2bf(b.z); o[7] = (short)f2bf(b.w);
  *(short8*)(out + (size_t)i * 8) = o;
}

__global__ __launch_bounds__(256) void cast_w4_kernel(const float* __restrict__ w0,
                                                      const float* __restrict__ w1,
                                                      const float* __restrict__ w2,
                                                      const float* __restrict__ w3,
                                                      unsigned short* __restrict__ o0,
                                                      unsigned short* __restrict__ o1,
                                                      unsigned short* __restrict__ o2,
                                                      unsigned short* __restrict__ o3){
  const int z = blockIdx.y;
  const float* in = (z == 0) ? w0 : (z == 1) ? w1 : (z == 2) ? w2 : w3;
  unsigned short* out = (z == 0) ? o0 : (z == 1) ? o1 : (z == 2) ? o2 : o3;
  int i = blockIdx.x * 256 + threadIdx.x;
  const float4* p = (const float4*)in + (size_t)i * 2;
  float4 a = p[0], b = p[1];
  short8 o;
  o[0] = (short)f2bf(a.x); o[1] = (short)f2bf(a.y); o[2] = (short)f2bf(a.z); o[3] = (short)f2bf(a.w);
  o[4] = (short)f2bf(b.x); o[5] = (short)f2bf(b.y); o[6] = (short)f2bf(b.z); o[7] = (short)f2bf(b.w);
  *(short8*)(out + (size_t)i * 8) = o;
}

// ---------------- NT GEMM 8-phase: 256x128 tile, BK=64, tri-buffer, counted vmcnt ----------------
// QKV only.  512 threads = 8 waves (4M x 2N), wave tile 64x64 (acc 64 VGPR).
// Tri-buffered LDS (144KB): during tile kt, tile kt+2's 6 load-groups are issued
// spread across 4 phases; tile-entry wait is vmcnt(6) (kt+1's 6 stay in flight) --
// never drains in the main loop (T3+T4).  Each phase: {ds_read || stage-issue} ->
// barrier -> lgkmcnt(0)+sched_barrier (rule 18) -> setprio(1) -> 8 MFMA ->
// setprio(0) -> barrier.  Staging uses the proven source-side XOR swizzle.
__global__ __launch_bounds__(512) void gemm_qkv_8p(
    const unsigned short* __restrict__ A,
    const unsigned short* __restrict__ B0, const unsigned short* __restrict__ B1,
    const unsigned short* __restrict__ B2,
    unsigned short* __restrict__ q0, unsigned short* __restrict__ q1, unsigned short* __restrict__ q2,
    int M, int N, int K)
{
  __shared__ __attribute__((aligned(16))) unsigned short As[3][256 * 64]; // 96KB
  __shared__ __attribute__((aligned(16))) unsigned short Bs[3][128 * 64]; // 48KB
  const int z = blockIdx.y;
  const unsigned short* __restrict__ B = (z == 0) ? B0 : ((z == 1) ? B1 : B2);
  unsigned short* __restrict__ qo = (z == 0) ? q0 : ((z == 1) ? q1 : q2);
  const int ntn = N >> 7;                       // 8
  const int nwg = gridDim.x, cpx = nwg >> 3;    // 256 -> 32
  const int bid = blockIdx.x;
  const int swz = (bid & 7) * cpx + (bid >> 3);
  const int tm = swz / ntn, tn = swz % ntn;
  const int m0 = tm << 8, n0 = tn << 7;
  const int t = threadIdx.x;
  const int w = t >> 6, l = t & 63, lo = l & 15, hi = l >> 4;
  const int wr = w >> 1, wc = w & 1;

  f32x4 acc[4][4];
#pragma unroll
  for (int i = 0; i < 4; ++i)
#pragma unroll
    for (int j = 0; j < 4; ++j) acc[i][j] = (f32x4){0.f, 0.f, 0.f, 0.f};

  // staging: thread covers A rows {srow+0,64,128,192}, B rows {srow+0,64};
  // source-side swizzle us = (l&7)^(srow&7), invariant across +64 row chunks.
  const int srow = t >> 3;                      // 0..63
  const int us = (l & 7) ^ (srow & 7);
  const unsigned short* gA = A + (size_t)(m0 + srow) * K + us * 8;
  const unsigned short* gB = B + (size_t)(n0 + srow) * K + us * 8;

  // read-side swizzled unit offsets (elems) per k-half
  const int u0 = ((0 * 4 + hi) ^ (lo & 7)) * 8;
  const int u1 = ((1 * 4 + hi) ^ (lo & 7)) * 8;

#define STG_A2(sb, kt2, i0) do { \
    g2lds16(gA + (size_t)((i0) * 64) * K + (kt2) * 64,        &As[sb][((i0) * 64 + w * 8) * 64]); \
    g2lds16(gA + (size_t)((i0) * 64 + 64) * K + (kt2) * 64,   &As[sb][((i0) * 64 + 64 + w * 8) * 64]); \
  } while (0)
#define STG_B1(sb, kt2, i0) \
    g2lds16(gB + (size_t)((i0) * 64) * K + (kt2) * 64,        &Bs[sb][((i0) * 64 + w * 8) * 64])

  // prologue: stage kt=0 (buf0) and kt=1 (buf1); wait only for kt=0's 6
  STG_A2(0, 0, 0); STG_A2(0, 0, 2); STG_B1(0, 0, 0); STG_B1(0, 0, 1);
  STG_A2(1, 1, 0); STG_A2(1, 1, 2); STG_B1(1, 1, 0); STG_B1(1, 1, 1);
  asm volatile("s_waitcnt vmcnt(6)" ::: "memory");
  __builtin_amdgcn_s_barrier();
  __builtin_amdgcn_sched_barrier(0);

  const int KT = K >> 6;                        // 16
  int buf = 0;
#pragma unroll 1
  for (int kt = 0; kt < KT; ++kt){
    const unsigned short* Ab = &As[buf][0];
    const unsigned short* Bb = &Bs[buf][0];
    const int sb = (buf >= 1) ? (buf - 1) : 2;  // (kt+2)%3
    const bool st = (kt + 2) < KT;
    short8 af[4], bf[4];

    // ---------------- P0: af(kh0) + bf(kh0, nf0..1) ; stage A01 ----------------
#pragma unroll
    for (int mf = 0; mf < 4; ++mf)
      af[mf] = *(const short8*)&Ab[(wr * 64 + mf * 16 + lo) * 64 + u0];
    bf[0] = *(const short8*)&Bb[(wc * 64 + 0 * 16 + lo) * 64 + u0];
    bf[1] = *(const short8*)&Bb[(wc * 64 + 1 * 16 + lo) * 64 + u0];
    if (st) STG_A2(sb, kt + 2, 0);
    __builtin_amdgcn_s_barrier();
    asm volatile("s_waitcnt lgkmcnt(0)" ::: "memory");
    __builtin_amdgcn_sched_barrier(0);
    __builtin_amdgcn_s_setprio(1);
#pragma unroll
    for (int mf = 0; mf < 4; ++mf){
      acc[mf][0] = __builtin_amdgcn_mfma_f32_16x16x32_bf16(af[mf], bf[0], acc[mf][0], 0, 0, 0);
      acc[mf][1] = __builtin_amdgcn_mfma_f32_16x16x32_bf16(af[mf], bf[1], acc[mf][1], 0, 0, 0);
    }
    __builtin_amdgcn_s_setprio(0);
    __builtin_amdgcn_s_barrier();

    // ---------------- P1: bf(kh0, nf2..3) ; stage A23 ----------------
    bf[2] = *(const short8*)&Bb[(wc * 64 + 2 * 16 + lo) * 64 + u0];
    bf[3] = *(const short8*)&Bb[(wc * 64 + 3 * 16 + lo) * 64 + u0];
    if (st) STG_A2(sb, kt + 2, 2);
    __builtin_amdgcn_s_barrier();
    asm volatile("s_waitcnt lgkmcnt(0)" ::: "memory");
    __builtin_amdgcn_sched_barrier(0);
    __builtin_amdgcn_s_setprio(1);
#pragma unroll
    for (int mf = 0; mf < 4; ++mf){
      acc[mf][2] = __builtin_amdgcn_mfma_f32_16x16x32_bf16(af[mf], bf[2], acc[mf][2], 0, 0, 0);
      acc[mf][3] = __builtin_amdgcn_mfma_f32_16x16x32_bf16(af[mf], bf[3], acc[mf][3], 0, 0, 0);
    }
    __builtin_amdgcn_s_setprio(0);
    __builtin_amdgcn_s_barrier();

    // ---------------- P2: af(kh1) + bf(kh1, nf0..1) ; stage B0 ----------------
#pragma unroll
    for (int mf = 0; mf < 4; ++mf)
      af[mf] = *(const short8*)&Ab[(wr * 64 + mf * 16 + lo) * 64 + u1];
    bf[0] = *(const short8*)&Bb[(wc * 64 + 0 * 16 + lo) * 64 + u1];
    bf[1] = *(const short8*)&Bb[(wc * 64 + 1 * 16 + lo) * 64 + u1];
    if (st) STG_B1(sb, kt + 2, 0);
    __builtin_amdgcn_s_barrier();
    asm volatile("s_waitcnt lgkmcnt(0)" ::: "memory");
    __builtin_amdgcn_sched_barrier(0);
    __builtin_amdgcn_s_setprio(1);
#pragma unroll
    for (int mf = 0; mf < 4; ++mf){
      acc[mf][0] = __builtin_amdgcn_mfma_f32_16x16x32_bf16(af[mf], bf[0], acc[mf][0], 0, 0, 0);
      acc[mf][1] = __builtin_amdgcn_mfma_f32_16x16x32_bf16(af[mf], bf[1], acc[mf][1], 0, 0, 0);
    }
    __builtin_amdgcn_s_setprio(0);
    __builtin_amdgcn_s_barrier();

    // ---------------- P3: bf(kh1, nf2..3) ; stage B1 ; tile-end vmcnt ----------------
    bf[2] = *(const short8*)&Bb[(wc * 64 + 2 * 16 + lo) * 64 + u1];
    bf[3] = *(const short8*)&Bb[(wc * 64 + 3 * 16 + lo) * 64 + u1];
    if (st) STG_B1(sb, kt + 2, 1);
    __builtin_amdgcn_s_barrier();
    asm volatile("s_waitcnt lgkmcnt(0)" ::: "memory");
    __builtin_amdgcn_sched_barrier(0);
    __builtin_amdgcn_s_setprio(1);
#pragma unroll
    for (int mf = 0; mf < 4; ++mf){
      acc[mf][2] = __builtin_amdgcn_mfma_f32_16x16x32_bf16(af[mf], bf[2], acc[mf][2], 0, 0, 0);
      acc[mf][3] = __builtin_amdgcn_mfma_f32_16x16x32_bf16(af[mf], bf[3], acc[mf][3], 0, 0, 0);
    }
    __builtin_amdgcn_s_setprio(0);
    if (kt + 1 < KT){
      if (kt + 2 < KT) asm volatile("s_waitcnt vmcnt(6)" ::: "memory");
      else             asm volatile("s_waitcnt vmcnt(0)" ::: "memory");
    }
    __builtin_amdgcn_s_barrier();
    __builtin_amdgcn_sched_barrier(0);
    buf = (buf == 2) ? 0 : buf + 1;
  }
#undef STG_A2
#undef STG_B1

  // ---- epilogue: Q/K natural scatter; V transposed (8B packed) ----
#pragma unroll
  for (int mf = 0; mf < 4; ++mf){
#pragma unroll
    for (int nf = 0; nf < 4; ++nf){
      if (z == 2){
        int m = m0 + wr * 64 + mf * 16 + hi * 4;
        int n = n0 + wc * 64 + nf * 16 + lo;
        int b = m >> 11, s = m & 2047, h = n >> 6, d = n & 63;
        ushort4v pk4;
        pk4[0] = f2bf(acc[mf][nf][0]);
        pk4[1] = f2bf(acc[mf][nf][1]);
        pk4[2] = f2bf(acc[mf][nf][2]);
        pk4[3] = f2bf(acc[mf][nf][3]);
        *(ushort4v*)&qo[(((size_t)(b * 16 + h)) * 64 + d) * 2048 + s] = pk4;
      } else {
#pragma unroll
        for (int j = 0; j < 4; ++j){
          int m = m0 + wr * 64 + mf * 16 + hi * 4 + j;
          int n = n0 + wc * 64 + nf * 16 + lo;
          int b = m >> 11, s = m & 2047, h = n >> 6, d = n & 63;
          qo[((((size_t)b * 16 + h) * 2048 + s) << 6) + d] = f2bf(acc[mf][nf][j]);
        }
      }
    }
  }
}

// ---------------- NT GEMM green (round-12/14): 128x128, BK=64 -- used for proj ----------------
template<int MODE>
__global__ __launch_bounds__(256) void gemm_nt(
    const unsigned short* __restrict__ A,
    const unsigned short* __restrict__ B0, const unsigned short* __restrict__ B1,
    const unsigned short* __restrict__ B2,
    unsigned short* __restrict__ q0, unsigned short* __restrict__ q1, unsigned short* __restrict__ q2,
    float* __restrict__ fout,
    int M, int N, int K)
{
  __shared__ __attribute__((aligned(16))) unsigned short As[128 * 64];
  __shared__ __attribute__((aligned(16))) unsigned short Bs[128 * 64];
  const int z = blockIdx.y;
  const unsigned short* __restrict__ B = (z == 0) ? B0 : ((z == 1) ? B1 : B2);
  unsigned short* __restrict__ qo = (z == 0) ? q0 : ((z == 1) ? q1 : q2);
  const int ntn = N >> 7;
  const int nwg = gridDim.x, cpx = nwg >> 3;
  const int bid = blockIdx.x;
  const int swz = (bid & 7) * cpx + (bid >> 3);
  const int tm = swz / ntn, tn = swz % ntn;
  const int m0 = tm << 7, n0 = tn << 7;
  const int t = threadIdx.x;
  const int w = t >> 6;
  const int l = t & 63, lo = l & 15, hi = l >> 4;
  const int wr = w >> 1, wc = w & 1;
  f32x4 acc[4][4];
#pragma unroll
  for (int i = 0; i < 4; ++i)
#pragma unroll
    for (int j = 0; j < 4; ++j) acc[i][j] = (f32x4){0.f, 0.f, 0.f, 0.f};

  const int srow = t >> 3;
  const int us = (l & 7) ^ (srow & 7);
  const unsigned short* gA = A + (size_t)(m0 + srow) * K + us * 8;
  const unsigned short* gB = B + (size_t)(n0 + srow) * K + us * 8;

  const int u0 = (((0 * 4 + hi) ^ (lo & 7)) * 8);
  const int u1 = (((1 * 4 + hi) ^ (lo & 7)) * 8);

  for (int kk = 0; kk < K; kk += 64){
#pragma unroll
    for (int i = 0; i < 4; ++i){
      g2lds16(gA + (size_t)(i * 32) * K + kk, &As[i * 2048 + w * 512]);
      g2lds16(gB + (size_t)(i * 32) * K + kk, &Bs[i * 2048 + w * 512]);
    }
    __syncthreads();
#pragma unroll
    for (int kh = 0; kh < 2; ++kh){
      const int uu = kh ? u1 : u0;
      short8 af[4], bf[4];
#pragma unroll
      for (int mf = 0; mf < 4; ++mf)
        af[mf] = *(const short8*)&As[(wr * 64 + mf * 16 + lo) * 64 + uu];
#pragma unroll
      for (int nf = 0; nf < 4; ++nf)
        bf[nf] = *(const short8*)&Bs[(wc * 64 + nf * 16 + lo) * 64 + uu];
      __builtin_amdgcn_s_setprio(1);
#pragma unroll
      for (int mf = 0; mf < 4; ++mf)
#pragma unroll
        for (int nf = 0; nf < 4; ++nf)
          acc[mf][nf] = __builtin_amdgcn_mfma_f32_16x16x32_bf16(af[mf], bf[nf], acc[mf][nf], 0, 0, 0);
      __builtin_amdgcn_s_setprio(0);
    }
    __syncthreads();
  }

#pragma unroll
  for (int mf = 0; mf < 4; ++mf){
#pragma unroll
    for (int nf = 0; nf < 4; ++nf){
      if (MODE == 0 && z == 2){
        int m = m0 + wr * 64 + mf * 16 + hi * 4;
        int n = n0 + wc * 64 + nf * 16 + lo;
        int b = m >> 11, s = m & 2047, h = n >> 6, d = n & 63;
        ushort4v pk4;
        pk4[0] = f2bf(acc[mf][nf][0]);
        pk4[1] = f2bf(acc[mf][nf][1]);
        pk4[2] = f2bf(acc[mf][nf][2]);
        pk4[3] = f2bf(acc[mf][nf][3]);
        *(ushort4v*)&qo[(((size_t)(b * 16 + h)) * 64 + d) * 2048 + s] = pk4;
      } else {
#pragma unroll
        for (int j = 0; j < 4; ++j){
          int m = m0 + wr * 64 + mf * 16 + hi * 4 + j;
          int n = n0 + wc * 64 + nf * 16 + lo;
          float v = acc[mf][nf][j];
          if (MODE == 0){
            int b = m >> 11, s = m & 2047, h = n >> 6, d = n & 63;
            qo[((((size_t)b * 16 + h) * 2048 + s) << 6) + d] = f2bf(v);
          } else {
            fout[(size_t)m * N + n] = v;
          }
        }
      }
    }
  }
}

// ---------------- causal flash attention v3 (round-6 verbatim, known-good 82us) ----------------
__global__ __launch_bounds__(256) void attn_kernel(
    const unsigned short* __restrict__ Q, const unsigned short* __restrict__ K,
    const unsigned short* __restrict__ Vt, unsigned short* __restrict__ O)
{
  __shared__ unsigned short Klds[2][64 * 64];
  __shared__ unsigned short Vlds[2][64 * 64];
  const int bid = blockIdx.x;               // 1024 blocks
  const int xcd = bid & 7, rank = bid >> 3; // rank 0..127
  const int bh = xcd * 8 + (rank >> 4);
  const int p = rank & 15;
  const int t = threadIdx.x, w = t >> 6, l = t & 63, lo = l & 15, hi = l >> 4;
  const size_t bb = (size_t)bh * 2048 * 64;
  const int bat = bh >> 4, h = bh & 15;
  const int srow0 = w * 8 + (l >> 3);
  const int su0 = l & 7;
  const float cexp = 0.125f * 1.44269504f;  // scale * log2(e)

#define STAGE(bufi, kv0) do { \
  _Pragma("unroll") \
  for (int i_ = 0; i_ < 2; ++i_){ \
    int row_ = i_ * 32 + srow0; \
    int us_ = su0 ^ (row_ & 7); \
    g2lds16(&K[bb + (size_t)((kv0) + row_) * 64 + us_ * 8], &Klds[bufi][i_ * 2048 + w * 512]); \
    g2lds16(&Vt[bb + (size_t)row_ * 2048 + (kv0) + us_ * 8], &Vlds[bufi][i_ * 2048 + w * 512]); \
  } \
} while (0)

#pragma unroll 1
  for (int ph = 0; ph < 2; ++ph){
    const int qt = ph ? (31 - p) : p;
    const int qr = qt * 64 + w * 16;
    short8 aq[2];
#pragma unroll
    for (int kg = 0; kg < 2; ++kg)
      aq[kg] = *(const short8*)&Q[bb + (size_t)(qr + lo) * 64 + kg * 32 + hi * 8];
    f32x4 accO[4];
#pragma unroll
    for (int i = 0; i < 4; ++i) accO[i] = (f32x4){0.f, 0.f, 0.f, 0.f};
    float m2 = -3e38f, lsum = 0.f;

    STAGE(0, 0);
    __syncthreads();
    int buf = 0;

#pragma unroll 1
    for (int s = 0; s <= qt; ++s){
      if (s < qt) STAGE(buf ^ 1, (s + 1) * 64);
      const unsigned short* Kl = &Klds[buf][0];
      const unsigned short* Vl = &Vlds[buf][0];
      f32x4 sa[4];
#pragma unroll
      for (int i = 0; i < 4; ++i) sa[i] = (f32x4){0.f, 0.f, 0.f, 0.f};
      __builtin_amdgcn_s_setprio(1);
#pragma unroll
      for (int ni = 0; ni < 4; ++ni)
#pragma unroll
        for (int kg = 0; kg < 2; ++kg){
          int u = (kg * 4 + hi) ^ (lo & 7);
          short8 kf = *(const short8*)&Kl[(ni * 16 + lo) * 64 + u * 8];
          sa[ni] = __builtin_amdgcn_mfma_f32_16x16x32_bf16(kf, aq[kg], sa[ni], 0, 0, 0);
        }
      __builtin_amdgcn_s_setprio(0);
      if (s == qt){
        const int qg = qr + lo;
        const int kv0 = s * 64;
#pragma unroll
        for (int ni = 0; ni < 4; ++ni)
#pragma unroll
          for (int j = 0; j < 4; ++j){
            int kv = kv0 + ni * 16 + hi * 4 + j;
            if (kv > qg) sa[ni][j] = -1e9f;
          }
      }
      float pm = fmaxf(fmaxf(sa[0][0], sa[0][1]), fmaxf(sa[0][2], sa[0][3]));
      pm = fmaxf(pm, fmaxf(fmaxf(sa[1][0], sa[1][1]), fmaxf(sa[1][2], sa[1][3])));
      pm = fmaxf(pm, fmaxf(fmaxf(sa[2][0], sa[2][1]), fmaxf(sa[2][2], sa[2][3])));
      pm = fmaxf(pm, fmaxf(fmaxf(sa[3][0], sa[3][1]), fmaxf(sa[3][2], sa[3][3])));
      float pms = pm * cexp;
      if (!__all(pms <= m2 + 8.0f)){
        float pr = fmaxf(pms, __shfl_xor(pms, 16, 64));
        pr = fmaxf(pr, __shfl_xor(pr, 32, 64));
        float m2n = fmaxf(m2, pr);
        float corr = exp2_fast(m2 - m2n);
        m2 = m2n;
        lsum *= corr;
        float cj[4];
#pragma unroll
        for (int j = 0; j < 4; ++j) cj[j] = __shfl(corr, hi * 4 + j, 64);
#pragma unroll
        for (int dt = 0; dt < 4; ++dt)
#pragma unroll
          for (int j = 0; j < 4; ++j) accO[dt][j] *= cj[j];
      }
      float rs = 0.f;
#pragma unroll
      for (int ni = 0; ni < 4; ++ni)
#pragma unroll
        for (int j = 0; j < 4; ++j){
          float pv = exp2_fast(fmaf(sa[ni][j], cexp, -m2));
          sa[ni][j] = pv;
          rs += pv;
        }
      rs += __shfl_xor(rs, 16, 64);
      rs += __shfl_xor(rs, 32, 64);
      lsum += rs;
      short8 pa[2];
#pragma unroll
      for (int kg = 0; kg < 2; ++kg){
        unsigned r0, r1, r2, r3;
        asm("v_cvt_pk_bf16_f32 %0, %1, %2" : "=v"(r0) : "v"(sa[2*kg][0]),   "v"(sa[2*kg][1]));
        asm("v_cvt_pk_bf16_f32 %0, %1, %2" : "=v"(r1) : "v"(sa[2*kg][2]),   "v"(sa[2*kg][3]));
        asm("v_cvt_pk_bf16_f32 %0, %1, %2" : "=v"(r2) : "v"(sa[2*kg+1][0]), "v"(sa[2*kg+1][1]));
        asm("v_cvt_pk_bf16_f32 %0, %1, %2" : "=v"(r3) : "v"(sa[2*kg+1][2]), "v"(sa[2*kg+1][3]));
        u32x4 pk; pk[0] = r0; pk[1] = r1; pk[2] = r2; pk[3] = r3;
        pa[kg] = __builtin_bit_cast(short8, pk);
      }
      __builtin_amdgcn_s_setprio(1);
#pragma unroll
      for (int dt = 0; dt < 4; ++dt)
#pragma unroll
        for (int kg = 0; kg < 2; ++kg){
          short4v c0, c1;
          {
            int u = ((kg * 2 + 0) * 2 + (hi >> 1)) ^ (lo & 7);
            c0 = *(const short4v*)&Vl[(dt * 16 + lo) * 64 + u * 8 + (hi & 1) * 4];
          }
          {
            int u = ((kg * 2 + 1) * 2 + (hi >> 1)) ^ (lo & 7);
            c1 = *(const short4v*)&Vl[(dt * 16 + lo) * 64 + u * 8 + (hi & 1) * 4];
          }
          short8 vb = (short8){c0[0], c0[1], c0[2], c0[3], c1[0], c1[1], c1[2], c1[3]};
          accO[dt] = __builtin_amdgcn_mfma_f32_16x16x32_bf16(pa[kg], vb, accO[dt], 0, 0, 0);
        }
      __builtin_amdgcn_s_setprio(0);
      __syncthreads();
      buf ^= 1;
    }
    float lr = 1.0f / lsum;
    float lj[4];
#pragma unroll
    for (int j = 0; j < 4; ++j) lj[j] = __shfl(lr, hi * 4 + j, 64);
#pragma unroll
    for (int dt = 0; dt < 4; ++dt)
#pragma unroll
      for (int j = 0; j < 4; ++j){
        int srow = qr + hi * 4 + j;
        O[((size_t)(bat * 2048 + srow) << 10) + h * 64 + dt * 16 + lo] = f2bf(accO[dt][j] * lj[j]);
      }
  }
#undef STAGE
}

extern "C" void kernel_launch(void* const* d_in, const int* in_sizes, int n_in,
                              void* d_out, int out_size, void* d_ws, size_t ws_size,
                              hipStream_t stream){
  (void)in_sizes; (void)n_in; (void)out_size; (void)ws_size;
  const float* x  = (const float*)d_in[0];
  const float* Wq = (const float*)d_in[1];
  const float* Wk = (const float*)d_in[2];
  const float* Wv = (const float*)d_in[3];
  const float* Wo = (const float*)d_in[4];
  char* ws = (char*)d_ws;
  const size_t MB = 1024 * 1024;
  unsigned short* XB  = (unsigned short*)(ws);            // 16MB (reused for O later)
  unsigned short* WQB = (unsigned short*)(ws + 16 * MB);  // 2MB each
  unsigned short* WKB = (unsigned short*)(ws + 18 * MB);
  unsigned short* WVB = (unsigned short*)(ws + 20 * MB);
  unsigned short* WOB = (unsigned short*)(ws + 22 * MB);
  unsigned short* Qb  = (unsigned short*)(ws + 24 * MB);  // 16MB each
  unsigned short* Kb  = (unsigned short*)(ws + 40 * MB);
  unsigned short* Vtb = (unsigned short*)(ws + 56 * MB);  // V written transposed by gemm
  unsigned short* Ob  = XB;

  cast_bf16_kernel<<<dim3(4096), 256, 0, stream>>>(x, XB, 8388608 / 8);
  cast_w4_kernel<<<dim3(512, 4), 256, 0, stream>>>(Wq, Wk, Wv, Wo, WQB, WKB, WVB, WOB);

  gemm_qkv_8p<<<dim3(256, 3), 512, 0, stream>>>(XB, WQB, WKB, WVB, Qb, Kb, Vtb,
                                                8192, 1024, 1024);
  attn_kernel<<<dim3(1024), 256, 0, stream>>>(Qb, Kb, Vtb, Ob);
  gemm_nt<1><<<dim3(512, 1), 256, 0, stream>>>(Ob, WOB, WOB, WOB, nullptr, nullptr, nullptr,
                                               (float*)d_out, 8192, 1024, 1024);
}

// Round 16
// 171.705 us; speedup vs baseline: 1.1078x; 1.1078x over previous
//
#include <hip/hip_runtime.h>

typedef __attribute__((ext_vector_type(8))) short short8;
typedef __attribute__((ext_vector_type(4))) short short4v;
typedef __attribute__((ext_vector_type(4))) unsigned short ushort4v;
typedef __attribute__((ext_vector_type(4))) float f32x4;
typedef __attribute__((ext_vector_type(4))) unsigned int u32x4;

static __device__ __forceinline__ unsigned short f2bf(float f){
  unsigned u = __builtin_bit_cast(unsigned, f);
  unsigned r = u + 0x7fffu + ((u >> 16) & 1u);
  return (unsigned short)(r >> 16);
}

static __device__ __forceinline__ float exp2_fast(float x){
  float r; asm("v_exp_f32 %0, %1" : "=v"(r) : "v"(x)); return r;
}

static __device__ __forceinline__ void g2lds16(const unsigned short* g, unsigned short* l){
  __builtin_amdgcn_global_load_lds(
      (const __attribute__((address_space(1))) void*)g,
      (__attribute__((address_space(3))) void*)l, 16, 0, 0);
}

// ---------------- cast fp32 -> bf16, x + 4 weights in ONE launch ----------------
// blocks 0..4095: x (8M elems); blocks 4096..6143: weights (4 x 1M elems).
__global__ __launch_bounds__(256) void cast_all_kernel(
    const float* __restrict__ x,
    const float* __restrict__ w0, const float* __restrict__ w1,
    const float* __restrict__ w2, const float* __restrict__ w3,
    unsigned short* __restrict__ ox,
    unsigned short* __restrict__ o0, unsigned short* __restrict__ o1,
    unsigned short* __restrict__ o2, unsigned short* __restrict__ o3){
  const int b = blockIdx.x;
  const float* in; unsigned short* out; int i0;
  if (b < 4096){ in = x; out = ox; i0 = b; }
  else {
    const int wb = b - 4096, z = wb >> 9; i0 = wb & 511;
    in  = (z == 0) ? w0 : (z == 1) ? w1 : (z == 2) ? w2 : w3;
    out = (z == 0) ? o0 : (z == 1) ? o1 : (z == 2) ? o2 : o3;
  }
  const int i = i0 * 256 + threadIdx.x;
  const float4* p = (const float4*)in + (size_t)i * 2;
  float4 a = p[0], bb = p[1];
  short8 o;
  o[0] = (short)f2bf(a.x);  o[1] = (short)f2bf(a.y);  o[2] = (short)f2bf(a.z);  o[3] = (short)f2bf(a.w);
  o[4] = (short)f2bf(bb.x); o[5] = (short)f2bf(bb.y); o[6] = (short)f2bf(bb.z); o[7] = (short)f2bf(bb.w);
  *(short8*)(out + (size_t)i * 8) = o;
}

// ---------------- NT GEMM green (round-12/14): 128x128, BK=64, swizzled staging ----------------
// MODE 0: bf16 scatter to [B][H][S][D] (z=0,1) and transposed Vt[bh][d][s] (z=2).
// MODE 1: fp32 row-major (final projection).
template<int MODE>
__global__ __launch_bounds__(256) void gemm_nt(
    const unsigned short* __restrict__ A,
    const unsigned short* __restrict__ B0, const unsigned short* __restrict__ B1,
    const unsigned short* __restrict__ B2,
    unsigned short* __restrict__ q0, unsigned short* __restrict__ q1, unsigned short* __restrict__ q2,
    float* __restrict__ fout,
    int M, int N, int K)
{
  __shared__ __attribute__((aligned(16))) unsigned short As[128 * 64]; // 16KB
  __shared__ __attribute__((aligned(16))) unsigned short Bs[128 * 64]; // 16KB
  const int z = blockIdx.y;
  const unsigned short* __restrict__ B = (z == 0) ? B0 : ((z == 1) ? B1 : B2);
  unsigned short* __restrict__ qo = (z == 0) ? q0 : ((z == 1) ? q1 : q2);
  const int ntn = N >> 7;
  const int nwg = gridDim.x, cpx = nwg >> 3;
  const int bid = blockIdx.x;
  const int swz = (bid & 7) * cpx + (bid >> 3);
  const int tm = swz / ntn, tn = swz % ntn;
  const int m0 = tm << 7, n0 = tn << 7;
  const int t = threadIdx.x;
  const int w = t >> 6;
  const int l = t & 63, lo = l & 15, hi = l >> 4;
  const int wr = w >> 1, wc = w & 1;
  f32x4 acc[4][4];
#pragma unroll
  for (int i = 0; i < 4; ++i)
#pragma unroll
    for (int j = 0; j < 4; ++j) acc[i][j] = (f32x4){0.f, 0.f, 0.f, 0.f};

  const int srow = t >> 3;                       // 0..31
  const int us = (l & 7) ^ (srow & 7);           // swizzled 16B unit (source side)
  const unsigned short* gA = A + (size_t)(m0 + srow) * K + us * 8;
  const unsigned short* gB = B + (size_t)(n0 + srow) * K + us * 8;

  const int u0 = (((0 * 4 + hi) ^ (lo & 7)) * 8);
  const int u1 = (((1 * 4 + hi) ^ (lo & 7)) * 8);

  for (int kk = 0; kk < K; kk += 64){
#pragma unroll
    for (int i = 0; i < 4; ++i){
      g2lds16(gA + (size_t)(i * 32) * K + kk, &As[i * 2048 + w * 512]);
      g2lds16(gB + (size_t)(i * 32) * K + kk, &Bs[i * 2048 + w * 512]);
    }
    __syncthreads();
#pragma unroll
    for (int kh = 0; kh < 2; ++kh){
      const int uu = kh ? u1 : u0;
      short8 af[4], bf[4];
#pragma unroll
      for (int mf = 0; mf < 4; ++mf)
        af[mf] = *(const short8*)&As[(wr * 64 + mf * 16 + lo) * 64 + uu];
#pragma unroll
      for (int nf = 0; nf < 4; ++nf)
        bf[nf] = *(const short8*)&Bs[(wc * 64 + nf * 16 + lo) * 64 + uu];
      __builtin_amdgcn_s_setprio(1);
#pragma unroll
      for (int mf = 0; mf < 4; ++mf)
#pragma unroll
        for (int nf = 0; nf < 4; ++nf)
          acc[mf][nf] = __builtin_amdgcn_mfma_f32_16x16x32_bf16(af[mf], bf[nf], acc[mf][nf], 0, 0, 0);
      __builtin_amdgcn_s_setprio(0);
    }
    __syncthreads();
  }

#pragma unroll
  for (int mf = 0; mf < 4; ++mf){
#pragma unroll
    for (int nf = 0; nf < 4; ++nf){
      if (MODE == 0 && z == 2){
        // V: write transposed Vt[bh][d][s]; j=0..3 -> s..s+3 contiguous (8B store)
        int m = m0 + wr * 64 + mf * 16 + hi * 4;       // j = 0
        int n = n0 + wc * 64 + nf * 16 + lo;
        int b = m >> 11, s = m & 2047, h = n >> 6, d = n & 63;
        ushort4v pk4;
        pk4[0] = f2bf(acc[mf][nf][0]);
        pk4[1] = f2bf(acc[mf][nf][1]);
        pk4[2] = f2bf(acc[mf][nf][2]);
        pk4[3] = f2bf(acc[mf][nf][3]);
        *(ushort4v*)&qo[(((size_t)(b * 16 + h)) * 64 + d) * 2048 + s] = pk4;
      } else {
#pragma unroll
        for (int j = 0; j < 4; ++j){
          int m = m0 + wr * 64 + mf * 16 + hi * 4 + j;
          int n = n0 + wc * 64 + nf * 16 + lo;
          float v = acc[mf][nf][j];
          if (MODE == 0){
            int b = m >> 11, s = m & 2047, h = n >> 6, d = n & 63;
            qo[((((size_t)b * 16 + h) * 2048 + s) << 6) + d] = f2bf(v);
          } else {
            fout[(size_t)m * N + n] = v;
          }
        }
      }
    }
  }
}

// ---------------- causal flash attention v3 (round-6 verbatim, known-good 82us) ----------------
__global__ __launch_bounds__(256) void attn_kernel(
    const unsigned short* __restrict__ Q, const unsigned short* __restrict__ K,
    const unsigned short* __restrict__ Vt, unsigned short* __restrict__ O)
{
  __shared__ unsigned short Klds[2][64 * 64];
  __shared__ unsigned short Vlds[2][64 * 64];
  const int bid = blockIdx.x;               // 1024 blocks
  const int xcd = bid & 7, rank = bid >> 3; // rank 0..127
  const int bh = xcd * 8 + (rank >> 4);
  const int p = rank & 15;
  const int t = threadIdx.x, w = t >> 6, l = t & 63, lo = l & 15, hi = l >> 4;
  const size_t bb = (size_t)bh * 2048 * 64;
  const int bat = bh >> 4, h = bh & 15;
  const int srow0 = w * 8 + (l >> 3);
  const int su0 = l & 7;
  const float cexp = 0.125f * 1.44269504f;  // scale * log2(e)

#define STAGE(bufi, kv0) do { \
  _Pragma("unroll") \
  for (int i_ = 0; i_ < 2; ++i_){ \
    int row_ = i_ * 32 + srow0; \
    int us_ = su0 ^ (row_ & 7); \
    g2lds16(&K[bb + (size_t)((kv0) + row_) * 64 + us_ * 8], &Klds[bufi][i_ * 2048 + w * 512]); \
    g2lds16(&Vt[bb + (size_t)row_ * 2048 + (kv0) + us_ * 8], &Vlds[bufi][i_ * 2048 + w * 512]); \
  } \
} while (0)

#pragma unroll 1
  for (int ph = 0; ph < 2; ++ph){
    const int qt = ph ? (31 - p) : p;
    const int qr = qt * 64 + w * 16;
    short8 aq[2];
#pragma unroll
    for (int kg = 0; kg < 2; ++kg)
      aq[kg] = *(const short8*)&Q[bb + (size_t)(qr + lo) * 64 + kg * 32 + hi * 8];
    f32x4 accO[4];
#pragma unroll
    for (int i = 0; i < 4; ++i) accO[i] = (f32x4){0.f, 0.f, 0.f, 0.f};
    float m2 = -3e38f, lsum = 0.f;

    STAGE(0, 0);
    __syncthreads();
    int buf = 0;

#pragma unroll 1
    for (int s = 0; s <= qt; ++s){
      if (s < qt) STAGE(buf ^ 1, (s + 1) * 64);
      const unsigned short* Kl = &Klds[buf][0];
      const unsigned short* Vl = &Vlds[buf][0];
      // ---- QK^T swapped: lane q=lo, kv = ni*16 + hi*4 + j ----
      f32x4 sa[4];
#pragma unroll
      for (int i = 0; i < 4; ++i) sa[i] = (f32x4){0.f, 0.f, 0.f, 0.f};
      __builtin_amdgcn_s_setprio(1);
#pragma unroll
      for (int ni = 0; ni < 4; ++ni)
#pragma unroll
        for (int kg = 0; kg < 2; ++kg){
          int u = (kg * 4 + hi) ^ (lo & 7);
          short8 kf = *(const short8*)&Kl[(ni * 16 + lo) * 64 + u * 8];
          sa[ni] = __builtin_amdgcn_mfma_f32_16x16x32_bf16(kf, aq[kg], sa[ni], 0, 0, 0);
        }
      __builtin_amdgcn_s_setprio(0);
      // ---- causal mask (raw domain), diag step only ----
      if (s == qt){
        const int qg = qr + lo;
        const int kv0 = s * 64;
#pragma unroll
        for (int ni = 0; ni < 4; ++ni)
#pragma unroll
          for (int j = 0; j < 4; ++j){
            int kv = kv0 + ni * 16 + hi * 4 + j;
            if (kv > qg) sa[ni][j] = -1e9f;
          }
      }
      // ---- online softmax, exp2 domain, defer-max ----
      float pm = fmaxf(fmaxf(sa[0][0], sa[0][1]), fmaxf(sa[0][2], sa[0][3]));
      pm = fmaxf(pm, fmaxf(fmaxf(sa[1][0], sa[1][1]), fmaxf(sa[1][2], sa[1][3])));
      pm = fmaxf(pm, fmaxf(fmaxf(sa[2][0], sa[2][1]), fmaxf(sa[2][2], sa[2][3])));
      pm = fmaxf(pm, fmaxf(fmaxf(sa[3][0], sa[3][1]), fmaxf(sa[3][2], sa[3][3])));
      float pms = pm * cexp;
      if (!__all(pms <= m2 + 8.0f)){
        float pr = fmaxf(pms, __shfl_xor(pms, 16, 64));
        pr = fmaxf(pr, __shfl_xor(pr, 32, 64));
        float m2n = fmaxf(m2, pr);
        float corr = exp2_fast(m2 - m2n);
        m2 = m2n;
        lsum *= corr;
        float cj[4];
#pragma unroll
        for (int j = 0; j < 4; ++j) cj[j] = __shfl(corr, hi * 4 + j, 64);
#pragma unroll
        for (int dt = 0; dt < 4; ++dt)
#pragma unroll
          for (int j = 0; j < 4; ++j) accO[dt][j] *= cj[j];
      }
      float rs = 0.f;
#pragma unroll
      for (int ni = 0; ni < 4; ++ni)
#pragma unroll
        for (int j = 0; j < 4; ++j){
          float pv = exp2_fast(fmaf(sa[ni][j], cexp, -m2));
          sa[ni][j] = pv;
          rs += pv;
        }
      rs += __shfl_xor(rs, 16, 64);
      rs += __shfl_xor(rs, 32, 64);
      lsum += rs;
      // ---- pack P via v_cvt_pk_bf16_f32 (dst.lo=src0, dst.hi=src1) ----
      short8 pa[2];
#pragma unroll
      for (int kg = 0; kg < 2; ++kg){
        unsigned r0, r1, r2, r3;
        asm("v_cvt_pk_bf16_f32 %0, %1, %2" : "=v"(r0) : "v"(sa[2*kg][0]),   "v"(sa[2*kg][1]));
        asm("v_cvt_pk_bf16_f32 %0, %1, %2" : "=v"(r1) : "v"(sa[2*kg][2]),   "v"(sa[2*kg][3]));
        asm("v_cvt_pk_bf16_f32 %0, %1, %2" : "=v"(r2) : "v"(sa[2*kg+1][0]), "v"(sa[2*kg+1][1]));
        asm("v_cvt_pk_bf16_f32 %0, %1, %2" : "=v"(r3) : "v"(sa[2*kg+1][2]), "v"(sa[2*kg+1][3]));
        u32x4 pk; pk[0] = r0; pk[1] = r1; pk[2] = r2; pk[3] = r3;
        pa[kg] = __builtin_bit_cast(short8, pk);
      }
      // ---- PV: B(V) loaded with the SAME permuted k-map as pa ----
      __builtin_amdgcn_s_setprio(1);
#pragma unroll
      for (int dt = 0; dt < 4; ++dt)
#pragma unroll
        for (int kg = 0; kg < 2; ++kg){
          short4v c0, c1;
          {
            int u = ((kg * 2 + 0) * 2 + (hi >> 1)) ^ (lo & 7);
            c0 = *(const short4v*)&Vl[(dt * 16 + lo) * 64 + u * 8 + (hi & 1) * 4];
          }
          {
            int u = ((kg * 2 + 1) * 2 + (hi >> 1)) ^ (lo & 7);
            c1 = *(const short4v*)&Vl[(dt * 16 + lo) * 64 + u * 8 + (hi & 1) * 4];
          }
          short8 vb = (short8){c0[0], c0[1], c0[2], c0[3], c1[0], c1[1], c1[2], c1[3]};
          accO[dt] = __builtin_amdgcn_mfma_f32_16x16x32_bf16(pa[kg], vb, accO[dt], 0, 0, 0);
        }
      __builtin_amdgcn_s_setprio(0);
      __syncthreads();
      buf ^= 1;
    }
    // ---- epilogue ----
    float lr = 1.0f / lsum;
    float lj[4];
#pragma unroll
    for (int j = 0; j < 4; ++j) lj[j] = __shfl(lr, hi * 4 + j, 64);
#pragma unroll
    for (int dt = 0; dt < 4; ++dt)
#pragma unroll
      for (int j = 0; j < 4; ++j){
        int srow = qr + hi * 4 + j;
        O[((size_t)(bat * 2048 + srow) << 10) + h * 64 + dt * 16 + lo] = f2bf(accO[dt][j] * lj[j]);
      }
  }
#undef STAGE
}

extern "C" void kernel_launch(void* const* d_in, const int* in_sizes, int n_in,
                              void* d_out, int out_size, void* d_ws, size_t ws_size,
                              hipStream_t stream){
  (void)in_sizes; (void)n_in; (void)out_size; (void)ws_size;
  const float* x  = (const float*)d_in[0];
  const float* Wq = (const float*)d_in[1];
  const float* Wk = (const float*)d_in[2];
  const float* Wv = (const float*)d_in[3];
  const float* Wo = (const float*)d_in[4];
  char* ws = (char*)d_ws;
  const size_t MB = 1024 * 1024;
  unsigned short* XB  = (unsigned short*)(ws);            // 16MB (reused for O later)
  unsigned short* WQB = (unsigned short*)(ws + 16 * MB);  // 2MB each
  unsigned short* WKB = (unsigned short*)(ws + 18 * MB);
  unsigned short* WVB = (unsigned short*)(ws + 20 * MB);
  unsigned short* WOB = (unsigned short*)(ws + 22 * MB);
  unsigned short* Qb  = (unsigned short*)(ws + 24 * MB);  // 16MB each
  unsigned short* Kb  = (unsigned short*)(ws + 40 * MB);
  unsigned short* Vtb = (unsigned short*)(ws + 56 * MB);  // V written transposed by gemm
  unsigned short* Ob  = XB;

  cast_all_kernel<<<dim3(6144), 256, 0, stream>>>(x, Wq, Wk, Wv, Wo,
                                                  XB, WQB, WKB, WVB, WOB);

  gemm_nt<0><<<dim3(512, 3), 256, 0, stream>>>(XB, WQB, WKB, WVB, Qb, Kb, Vtb, nullptr,
                                               8192, 1024, 1024);
  attn_kernel<<<dim3(1024), 256, 0, stream>>>(Qb, Kb, Vtb, Ob);
  gemm_nt<1><<<dim3(512, 1), 256, 0, stream>>>(Ob, WOB, WOB, WOB, nullptr, nullptr, nullptr,
                                               (float*)d_out, 8192, 1024, 1024);
}

// Round 17
// 171.588 us; speedup vs baseline: 1.1085x; 1.0007x over previous
//
#include <hip/hip_runtime.h>

typedef __attribute__((ext_vector_type(8))) short short8;
typedef __attribute__((ext_vector_type(4))) short short4v;
typedef __attribute__((ext_vector_type(4))) unsigned short ushort4v;
typedef __attribute__((ext_vector_type(4))) float f32x4;
typedef __attribute__((ext_vector_type(4))) unsigned int u32x4;

static __device__ __forceinline__ unsigned short f2bf(float f){
  unsigned u = __builtin_bit_cast(unsigned, f);
  unsigned r = u + 0x7fffu + ((u >> 16) & 1u);
  return (unsigned short)(r >> 16);
}

static __device__ __forceinline__ float exp2_fast(float x){
  float r; asm("v_exp_f32 %0, %1" : "=v"(r) : "v"(x)); return r;
}
static __device__ __forceinline__ float max3f(float a, float b, float c){
  float r; asm("v_max3_f32 %0, %1, %2, %3" : "=v"(r) : "v"(a), "v"(b), "v"(c)); return r;
}

static __device__ __forceinline__ void g2lds16(const unsigned short* g, unsigned short* l){
  __builtin_amdgcn_global_load_lds(
      (const __attribute__((address_space(1))) void*)g,
      (__attribute__((address_space(3))) void*)l, 16, 0, 0);
}

// ---------------- cast fp32 -> bf16, x + 4 weights in ONE launch ----------------
// blocks 0..4095: x (8M elems); blocks 4096..6143: weights (4 x 1M elems).
__global__ __launch_bounds__(256) void cast_all_kernel(
    const float* __restrict__ x,
    const float* __restrict__ w0, const float* __restrict__ w1,
    const float* __restrict__ w2, const float* __restrict__ w3,
    unsigned short* __restrict__ ox,
    unsigned short* __restrict__ o0, unsigned short* __restrict__ o1,
    unsigned short* __restrict__ o2, unsigned short* __restrict__ o3){
  const int b = blockIdx.x;
  const float* in; unsigned short* out; int i0;
  if (b < 4096){ in = x; out = ox; i0 = b; }
  else {
    const int wb = b - 4096, z = wb >> 9; i0 = wb & 511;
    in  = (z == 0) ? w0 : (z == 1) ? w1 : (z == 2) ? w2 : w3;
    out = (z == 0) ? o0 : (z == 1) ? o1 : (z == 2) ? o2 : o3;
  }
  const int i = i0 * 256 + threadIdx.x;
  const float4* p = (const float4*)in + (size_t)i * 2;
  float4 a = p[0], bb = p[1];
  short8 o;
  o[0] = (short)f2bf(a.x);  o[1] = (short)f2bf(a.y);  o[2] = (short)f2bf(a.z);  o[3] = (short)f2bf(a.w);
  o[4] = (short)f2bf(bb.x); o[5] = (short)f2bf(bb.y); o[6] = (short)f2bf(bb.z); o[7] = (short)f2bf(bb.w);
  *(short8*)(out + (size_t)i * 8) = o;
}

// ---------------- NT GEMM green (round-12/14): 128x128, BK=64, swizzled staging ----------------
// MODE 0: bf16 scatter to [B][H][S][D] (z=0,1) and transposed Vt[bh][d][s] (z=2).
// MODE 1: fp32 row-major (final projection).
template<int MODE>
__global__ __launch_bounds__(256) void gemm_nt(
    const unsigned short* __restrict__ A,
    const unsigned short* __restrict__ B0, const unsigned short* __restrict__ B1,
    const unsigned short* __restrict__ B2,
    unsigned short* __restrict__ q0, unsigned short* __restrict__ q1, unsigned short* __restrict__ q2,
    float* __restrict__ fout,
    int M, int N, int K)
{
  __shared__ __attribute__((aligned(16))) unsigned short As[128 * 64]; // 16KB
  __shared__ __attribute__((aligned(16))) unsigned short Bs[128 * 64]; // 16KB
  const int z = blockIdx.y;
  const unsigned short* __restrict__ B = (z == 0) ? B0 : ((z == 1) ? B1 : B2);
  unsigned short* __restrict__ qo = (z == 0) ? q0 : ((z == 1) ? q1 : q2);
  const int ntn = N >> 7;
  const int nwg = gridDim.x, cpx = nwg >> 3;
  const int bid = blockIdx.x;
  const int swz = (bid & 7) * cpx + (bid >> 3);
  const int tm = swz / ntn, tn = swz % ntn;
  const int m0 = tm << 7, n0 = tn << 7;
  const int t = threadIdx.x;
  const int w = t >> 6;
  const int l = t & 63, lo = l & 15, hi = l >> 4;
  const int wr = w >> 1, wc = w & 1;
  f32x4 acc[4][4];
#pragma unroll
  for (int i = 0; i < 4; ++i)
#pragma unroll
    for (int j = 0; j < 4; ++j) acc[i][j] = (f32x4){0.f, 0.f, 0.f, 0.f};

  const int srow = t >> 3;                       // 0..31
  const int us = (l & 7) ^ (srow & 7);           // swizzled 16B unit (source side)
  const unsigned short* gA = A + (size_t)(m0 + srow) * K + us * 8;
  const unsigned short* gB = B + (size_t)(n0 + srow) * K + us * 8;

  const int u0 = (((0 * 4 + hi) ^ (lo & 7)) * 8);
  const int u1 = (((1 * 4 + hi) ^ (lo & 7)) * 8);

  for (int kk = 0; kk < K; kk += 64){
#pragma unroll
    for (int i = 0; i < 4; ++i){
      g2lds16(gA + (size_t)(i * 32) * K + kk, &As[i * 2048 + w * 512]);
      g2lds16(gB + (size_t)(i * 32) * K + kk, &Bs[i * 2048 + w * 512]);
    }
    __syncthreads();
#pragma unroll
    for (int kh = 0; kh < 2; ++kh){
      const int uu = kh ? u1 : u0;
      short8 af[4], bf[4];
#pragma unroll
      for (int mf = 0; mf < 4; ++mf)
        af[mf] = *(const short8*)&As[(wr * 64 + mf * 16 + lo) * 64 + uu];
#pragma unroll
      for (int nf = 0; nf < 4; ++nf)
        bf[nf] = *(const short8*)&Bs[(wc * 64 + nf * 16 + lo) * 64 + uu];
      __builtin_amdgcn_s_setprio(1);
#pragma unroll
      for (int mf = 0; mf < 4; ++mf)
#pragma unroll
        for (int nf = 0; nf < 4; ++nf)
          acc[mf][nf] = __builtin_amdgcn_mfma_f32_16x16x32_bf16(af[mf], bf[nf], acc[mf][nf], 0, 0, 0);
      __builtin_amdgcn_s_setprio(0);
    }
    __syncthreads();
  }

#pragma unroll
  for (int mf = 0; mf < 4; ++mf){
#pragma unroll
    for (int nf = 0; nf < 4; ++nf){
      if (MODE == 0 && z == 2){
        // V: write transposed Vt[bh][d][s]; j=0..3 -> s..s+3 contiguous (8B store)
        int m = m0 + wr * 64 + mf * 16 + hi * 4;       // j = 0
        int n = n0 + wc * 64 + nf * 16 + lo;
        int b = m >> 11, s = m & 2047, h = n >> 6, d = n & 63;
        ushort4v pk4;
        pk4[0] = f2bf(acc[mf][nf][0]);
        pk4[1] = f2bf(acc[mf][nf][1]);
        pk4[2] = f2bf(acc[mf][nf][2]);
        pk4[3] = f2bf(acc[mf][nf][3]);
        *(ushort4v*)&qo[(((size_t)(b * 16 + h)) * 64 + d) * 2048 + s] = pk4;
      } else {
#pragma unroll
        for (int j = 0; j < 4; ++j){
          int m = m0 + wr * 64 + mf * 16 + hi * 4 + j;
          int n = n0 + wc * 64 + nf * 16 + lo;
          float v = acc[mf][nf][j];
          if (MODE == 0){
            int b = m >> 11, s = m & 2047, h = n >> 6, d = n & 63;
            qo[((((size_t)b * 16 + h) * 2048 + s) << 6) + d] = f2bf(v);
          } else {
            fout[(size_t)m * N + n] = v;
          }
        }
      }
    }
  }
}

// ---------------- causal flash attention v3m (round-6 v3 + v_max3 gate tree) ----------------
__global__ __launch_bounds__(256) void attn_kernel(
    const unsigned short* __restrict__ Q, const unsigned short* __restrict__ K,
    const unsigned short* __restrict__ Vt, unsigned short* __restrict__ O)
{
  __shared__ unsigned short Klds[2][64 * 64];
  __shared__ unsigned short Vlds[2][64 * 64];
  const int bid = blockIdx.x;               // 1024 blocks
  const int xcd = bid & 7, rank = bid >> 3; // rank 0..127
  const int bh = xcd * 8 + (rank >> 4);
  const int p = rank & 15;
  const int t = threadIdx.x, w = t >> 6, l = t & 63, lo = l & 15, hi = l >> 4;
  const size_t bb = (size_t)bh * 2048 * 64;
  const int bat = bh >> 4, h = bh & 15;
  const int srow0 = w * 8 + (l >> 3);
  const int su0 = l & 7;
  const float cexp = 0.125f * 1.44269504f;  // scale * log2(e)

#define STAGE(bufi, kv0) do { \
  _Pragma("unroll") \
  for (int i_ = 0; i_ < 2; ++i_){ \
    int row_ = i_ * 32 + srow0; \
    int us_ = su0 ^ (row_ & 7); \
    g2lds16(&K[bb + (size_t)((kv0) + row_) * 64 + us_ * 8], &Klds[bufi][i_ * 2048 + w * 512]); \
    g2lds16(&Vt[bb + (size_t)row_ * 2048 + (kv0) + us_ * 8], &Vlds[bufi][i_ * 2048 + w * 512]); \
  } \
} while (0)

#pragma unroll 1
  for (int ph = 0; ph < 2; ++ph){
    const int qt = ph ? (31 - p) : p;
    const int qr = qt * 64 + w * 16;
    short8 aq[2];
#pragma unroll
    for (int kg = 0; kg < 2; ++kg)
      aq[kg] = *(const short8*)&Q[bb + (size_t)(qr + lo) * 64 + kg * 32 + hi * 8];
    f32x4 accO[4];
#pragma unroll
    for (int i = 0; i < 4; ++i) accO[i] = (f32x4){0.f, 0.f, 0.f, 0.f};
    float m2 = -3e38f, lsum = 0.f;

    STAGE(0, 0);
    __syncthreads();
    int buf = 0;

#pragma unroll 1
    for (int s = 0; s <= qt; ++s){
      if (s < qt) STAGE(buf ^ 1, (s + 1) * 64);
      const unsigned short* Kl = &Klds[buf][0];
      const unsigned short* Vl = &Vlds[buf][0];
      // ---- QK^T swapped: lane q=lo, kv = ni*16 + hi*4 + j ----
      f32x4 sa[4];
#pragma unroll
      for (int i = 0; i < 4; ++i) sa[i] = (f32x4){0.f, 0.f, 0.f, 0.f};
      __builtin_amdgcn_s_setprio(1);
#pragma unroll
      for (int ni = 0; ni < 4; ++ni)
#pragma unroll
        for (int kg = 0; kg < 2; ++kg){
          int u = (kg * 4 + hi) ^ (lo & 7);
          short8 kf = *(const short8*)&Kl[(ni * 16 + lo) * 64 + u * 8];
          sa[ni] = __builtin_amdgcn_mfma_f32_16x16x32_bf16(kf, aq[kg], sa[ni], 0, 0, 0);
        }
      __builtin_amdgcn_s_setprio(0);
      // ---- causal mask (raw domain), diag step only ----
      if (s == qt){
        const int qg = qr + lo;
        const int kv0 = s * 64;
#pragma unroll
        for (int ni = 0; ni < 4; ++ni)
#pragma unroll
          for (int j = 0; j < 4; ++j){
            int kv = kv0 + ni * 16 + hi * 4 + j;
            if (kv > qg) sa[ni][j] = -1e9f;
          }
      }
      // ---- online softmax, exp2 domain, defer-max; gate via v_max3 tree (v5-proven) ----
      float pa0 = max3f(sa[0][0], sa[0][1], sa[0][2]);
      float pa1 = max3f(sa[0][3], sa[1][0], sa[1][1]);
      float pa2 = max3f(sa[1][2], sa[1][3], sa[2][0]);
      float pa3 = max3f(sa[2][1], sa[2][2], sa[2][3]);
      float pa4 = max3f(sa[3][0], sa[3][1], sa[3][2]);
      float pm = fmaxf(max3f(pa0, pa1, pa2), max3f(pa3, pa4, sa[3][3]));
      float pms = pm * cexp;
      if (!__all(pms <= m2 + 8.0f)){
        float pr = fmaxf(pms, __shfl_xor(pms, 16, 64));
        pr = fmaxf(pr, __shfl_xor(pr, 32, 64));
        float m2n = fmaxf(m2, pr);
        float corr = exp2_fast(m2 - m2n);
        m2 = m2n;
        lsum *= corr;
        float cj[4];
#pragma unroll
        for (int j = 0; j < 4; ++j) cj[j] = __shfl(corr, hi * 4 + j, 64);
#pragma unroll
        for (int dt = 0; dt < 4; ++dt)
#pragma unroll
          for (int j = 0; j < 4; ++j) accO[dt][j] *= cj[j];
      }
      float rs = 0.f;
#pragma unroll
      for (int ni = 0; ni < 4; ++ni)
#pragma unroll
        for (int j = 0; j < 4; ++j){
          float pv = exp2_fast(fmaf(sa[ni][j], cexp, -m2));
          sa[ni][j] = pv;
          rs += pv;
        }
      rs += __shfl_xor(rs, 16, 64);
      rs += __shfl_xor(rs, 32, 64);
      lsum += rs;
      // ---- pack P via v_cvt_pk_bf16_f32 (dst.lo=src0, dst.hi=src1) ----
      short8 pa[2];
#pragma unroll
      for (int kg = 0; kg < 2; ++kg){
        unsigned r0, r1, r2, r3;
        asm("v_cvt_pk_bf16_f32 %0, %1, %2" : "=v"(r0) : "v"(sa[2*kg][0]),   "v"(sa[2*kg][1]));
        asm("v_cvt_pk_bf16_f32 %0, %1, %2" : "=v"(r1) : "v"(sa[2*kg][2]),   "v"(sa[2*kg][3]));
        asm("v_cvt_pk_bf16_f32 %0, %1, %2" : "=v"(r2) : "v"(sa[2*kg+1][0]), "v"(sa[2*kg+1][1]));
        asm("v_cvt_pk_bf16_f32 %0, %1, %2" : "=v"(r3) : "v"(sa[2*kg+1][2]), "v"(sa[2*kg+1][3]));
        u32x4 pk; pk[0] = r0; pk[1] = r1; pk[2] = r2; pk[3] = r3;
        pa[kg] = __builtin_bit_cast(short8, pk);
      }
      // ---- PV: B(V) loaded with the SAME permuted k-map as pa ----
      __builtin_amdgcn_s_setprio(1);
#pragma unroll
      for (int dt = 0; dt < 4; ++dt)
#pragma unroll
        for (int kg = 0; kg < 2; ++kg){
          short4v c0, c1;
          {
            int u = ((kg * 2 + 0) * 2 + (hi >> 1)) ^ (lo & 7);
            c0 = *(const short4v*)&Vl[(dt * 16 + lo) * 64 + u * 8 + (hi & 1) * 4];
          }
          {
            int u = ((kg * 2 + 1) * 2 + (hi >> 1)) ^ (lo & 7);
            c1 = *(const short4v*)&Vl[(dt * 16 + lo) * 64 + u * 8 + (hi & 1) * 4];
          }
          short8 vb = (short8){c0[0], c0[1], c0[2], c0[3], c1[0], c1[1], c1[2], c1[3]};
          accO[dt] = __builtin_amdgcn_mfma_f32_16x16x32_bf16(pa[kg], vb, accO[dt], 0, 0, 0);
        }
      __builtin_amdgcn_s_setprio(0);
      __syncthreads();
      buf ^= 1;
    }
    // ---- epilogue ----
    float lr = 1.0f / lsum;
    float lj[4];
#pragma unroll
    for (int j = 0; j < 4; ++j) lj[j] = __shfl(lr, hi * 4 + j, 64);
#pragma unroll
    for (int dt = 0; dt < 4; ++dt)
#pragma unroll
      for (int j = 0; j < 4; ++j){
        int srow = qr + hi * 4 + j;
        O[((size_t)(bat * 2048 + srow) << 10) + h * 64 + dt * 16 + lo] = f2bf(accO[dt][j] * lj[j]);
      }
  }
#undef STAGE
}

extern "C" void kernel_launch(void* const* d_in, const int* in_sizes, int n_in,
                              void* d_out, int out_size, void* d_ws, size_t ws_size,
                              hipStream_t stream){
  (void)in_sizes; (void)n_in; (void)out_size; (void)ws_size;
  const float* x  = (const float*)d_in[0];
  const float* Wq = (const float*)d_in[1];
  const float* Wk = (const float*)d_in[2];
  const float* Wv = (const float*)d_in[3];
  const float* Wo = (const float*)d_in[4];
  char* ws = (char*)d_ws;
  const size_t MB = 1024 * 1024;
  unsigned short* XB  = (unsigned short*)(ws);            // 16MB (reused for O later)
  unsigned short* WQB = (unsigned short*)(ws + 16 * MB);  // 2MB each
  unsigned short* WKB = (unsigned short*)(ws + 18 * MB);
  unsigned short* WVB = (unsigned short*)(ws + 20 * MB);
  unsigned short* WOB = (unsigned short*)(ws + 22 * MB);
  unsigned short* Qb  = (unsigned short*)(ws + 24 * MB);  // 16MB each
  unsigned short* Kb  = (unsigned short*)(ws + 40 * MB);
  unsigned short* Vtb = (unsigned short*)(ws + 56 * MB);  // V written transposed by gemm
  unsigned short* Ob  = XB;

  cast_all_kernel<<<dim3(6144), 256, 0, stream>>>(x, Wq, Wk, Wv, Wo,
                                                  XB, WQB, WKB, WVB, WOB);

  gemm_nt<0><<<dim3(512, 3), 256, 0, stream>>>(XB, WQB, WKB, WVB, Qb, Kb, Vtb, nullptr,
                                               8192, 1024, 1024);
  attn_kernel<<<dim3(1024), 256, 0, stream>>>(Qb, Kb, Vtb, Ob);
  gemm_nt<1><<<dim3(512, 1), 256, 0, stream>>>(Ob, WOB, WOB, WOB, nullptr, nullptr, nullptr,
                                               (float*)d_out, 8192, 1024, 1024);
}